// Round 12
// baseline (235.048 us; speedup 1.0000x reference)
//
#include <hip/hip_runtime.h>
#include <hip/hip_bf16.h>
#include <cstdint>
#include <cstddef>

// B=4, S=2048, D=1024, H=16, DH=64.  M = B*S = 8192.
// fused cast (x + 4 weights); fused QKV GEMM (256x192 8-phase, counted-vmcnt,
// fused V-transpose epilogue); MFMA flash attention (single q-tile, dbuf K/V
// + __syncthreads loop, 3 blocks/CU, big-first dispatch, qt-priority ladder;
// O-store epilogue restaged through dead p_s for 16B/lane coalesced writes);
// output GEMM (256x128 6-phase, 1 clean round).
// Workspace 75,497,472 B: xb/attnb 16M | wqkv 6M | wo 2M | Q,K 32M | vT 16M.

typedef unsigned short u16;
typedef __bf16 bf16x8 __attribute__((ext_vector_type(8)));
typedef float  f32x4  __attribute__((ext_vector_type(4)));

__device__ __forceinline__ u16 f2bf(float f) {
  unsigned u = __float_as_uint(f);
  unsigned r = u + 0x7fffu + ((u >> 16) & 1u);   // RNE
  return (u16)(r >> 16);
}

// async global->LDS, 16B per lane (dest = wave-uniform base + lane*16)
__device__ __forceinline__ void llds16(const u16* g, u16* l) {
  __builtin_amdgcn_global_load_lds(
      (const __attribute__((address_space(1))) void*)g,
      (__attribute__((address_space(3))) void*)l, 16, 0, 0);
}

// ---------------- fused cast fp32 -> bf16 (x + Wq,Wk,Wv,Wo) ----------------
__global__ void cast_all_kernel(const float* __restrict__ x,
                                const float* __restrict__ Wq, const float* __restrict__ Wk,
                                const float* __restrict__ Wv, const float* __restrict__ Wo,
                                u16* __restrict__ xb, u16* __restrict__ wqkv,
                                u16* __restrict__ wo) {
  const int bid = (int)blockIdx.x;
  const int tid = threadIdx.x;
  if (bid < 8192) {
    const int i = (bid << 8) + tid;
    float4 f = ((const float4*)x)[i];
    ushort4 u;
    u.x = f2bf(f.x); u.y = f2bf(f.y); u.z = f2bf(f.z); u.w = f2bf(f.w);
    ((ushort4*)xb)[i] = u;
  } else {
    const int j = ((bid - 8192) << 8) + tid;   // 0..1048575
    const int w = j >> 18;                     // 0..3
    const int idx = j & 262143;
    const float* src = (w == 0) ? Wq : (w == 1) ? Wk : (w == 2) ? Wv : Wo;
    u16* dst = (w == 3) ? wo : (wqkv + (w << 20));
    float4 f = ((const float4*)src)[idx];
    ushort4 u;
    u.x = f2bf(f.x); u.y = f2bf(f.y); u.z = f2bf(f.z); u.w = f2bf(f.w);
    ((ushort4*)dst)[idx] = u;
  }
}

// ---------------- 256x192 8-phase QKV GEMM + fused V-transpose ----------------
__global__ __launch_bounds__(512) void gemm_qkv_256(
    const u16* __restrict__ A, const u16* __restrict__ Bw,
    const float* __restrict__ b0, const float* __restrict__ b1, const float* __restrict__ b2,
    u16* __restrict__ qkv_out, u16* __restrict__ vT_out)
{
  __shared__ u16 lds[57344];   // 112 KiB (reused as epilogue staging)

  const int tid = threadIdx.x;
  const int lane = tid & 63;
  const int wave = tid >> 6;

  // XCD-grouped decode: xcd = bid&7; each XCD owns 4 m-panels x all 16 n-tiles.
  const int bid = (int)blockIdx.x;
  const int xcd = bid & 7;
  const int idx = bid >> 3;                 // 0..63
  const int mt = (xcd << 2) | (idx & 3);    // 0..31
  const int nt = idx >> 2;                  // 0..15
  const int m0 = mt << 8;
  const int n0 = nt * 192;

  const int warp_m = wave >> 2;       // 0..1
  const int warp_n = wave & 3;        // 0..3
  const int wm = warp_m << 7;         // 0,128
  const int wn = warp_n * 48;         // 0,48,96,144
  const int fr = lane & 15;
  const int g  = lane >> 4;           // 0..3

  // staging source (pre-swizzled global addr so linear LDS dest lands swizzled)
  const int srow = tid >> 3;                       // 0..63
  const int schk = ((tid & 7) ^ (srow & 7)) << 3;  // stored chunk -> logical col
  const u16* pA = A  + (size_t)(m0 + srow) * 1024 + schk;
  const u16* pB = Bw + (size_t)(n0 + srow) * 1024 + schk;

  // fragment-read swizzled chunk offsets (chunk = s*4+g, stored = chunk^(row&7))
  const int rsw0 = ((g    ) ^ (fr & 7)) << 3;
  const int rsw1 = ((g ^ 4) ^ (fr & 7)) << 3;

  // read bases (include fr*64 row offset); buf stride 28672 u16
  const u16* Ab0 = lds + (size_t)(wm + fr) * 64;
  const u16* Bb0 = lds + 16384 + (size_t)(wn + fr) * 64;
  const u16* Ab1 = Ab0 + 28672;
  const u16* Bb1 = Bb0 + 28672;

  f32x4 acc[8][3];
  const f32x4 zero = {0.f, 0.f, 0.f, 0.f};
#pragma unroll
  for (int i = 0; i < 8; i++)
#pragma unroll
    for (int j = 0; j < 3; j++) acc[i][j] = zero;

  bf16x8 a_[4][2];
  bf16x8 b_[3][2];

  auto stageA = [&](int kt, int buf, int half) {   // 2 loads (128 rows)
    const u16* src = pA + (size_t)half * 131072 + (kt << 6);
    u16* dst = lds + buf * 28672 + half * 8192 + tid * 8;
    llds16(src, dst);
    llds16(src + 65536, dst + 4096);
  };
  auto stageB0 = [&](int kt, int buf) {            // 2 loads (rows 0-127)
    const u16* src = pB + (kt << 6);
    u16* dst = lds + buf * 28672 + 16384 + tid * 8;
    llds16(src, dst);
    llds16(src + 65536, dst + 4096);
  };
  auto stageB1 = [&](int kt, int buf) {            // 1 load (rows 128-191)
    const u16* src = pB + 131072 + (kt << 6);
    u16* dst = lds + buf * 28672 + 24576 + tid * 8;
    llds16(src, dst);
  };
  auto loadA4 = [&](const u16* Ab, int ib) {
#pragma unroll
    for (int ii = 0; ii < 4; ii++) {
      const u16* r = Ab + (ib + ii) * 1024;
      a_[ii][0] = *(const bf16x8*)(r + rsw0);
      a_[ii][1] = *(const bf16x8*)(r + rsw1);
    }
  };
  auto loadB = [&](const u16* Bb, int j0, int nj) {
#pragma unroll
    for (int jj = 0; jj < 3; jj++) {
      if (jj < nj) {
        const u16* r = Bb + (j0 + jj) * 1024;
        b_[j0 + jj][0] = *(const bf16x8*)(r + rsw0);
        b_[j0 + jj][1] = *(const bf16x8*)(r + rsw1);
      }
    }
  };
  auto mfmaQ = [&](int ib, int j0, int nj) {
    __builtin_amdgcn_s_setprio(1);
#pragma unroll
    for (int jj = 0; jj < 3; jj++) {
      if (jj < nj) {
#pragma unroll
        for (int ii = 0; ii < 4; ii++) {
          acc[ib+ii][j0+jj] = __builtin_amdgcn_mfma_f32_16x16x32_bf16(
              a_[ii][0], b_[j0+jj][0], acc[ib+ii][j0+jj], 0, 0, 0);
          acc[ib+ii][j0+jj] = __builtin_amdgcn_mfma_f32_16x16x32_bf16(
              a_[ii][1], b_[j0+jj][1], acc[ib+ii][j0+jj], 0, 0, 0);
        }
      }
    }
    __builtin_amdgcn_s_setprio(0);
  };

  // prologue: buf0 <- K-tile 0 (A0,A1,B0,B1 = 7 loads), buf1.A0 <- K-tile 1 (2)
  stageA(0, 0, 0);
  stageA(0, 0, 1);
  stageB0(0, 0);
  stageB1(0, 0);
  stageA(1, 1, 0);
  asm volatile("s_waitcnt vmcnt(2)" ::: "memory");  // tile0 landed; tile1.A0 in flight
  __builtin_amdgcn_s_barrier();

  const int NTI = 8;   // K / 128
  for (int t = 0; t < NTI; ++t) {
    const bool st = (t < NTI - 1);
    const int ka = 2 * t + 1;
    const int kb = 2 * t + 2;
    const int kc = 2 * t + 3;

    // ---- K-tile 2t from buf0 ----
    // p0
    loadA4(Ab0, 0); loadB(Bb0, 0, 2);
    stageA(ka, 1, 1);
    __builtin_amdgcn_s_barrier();
    mfmaQ(0, 0, 2);
    __builtin_amdgcn_s_barrier();
    // p1
    loadB(Bb0, 2, 1);
    stageB0(ka, 1);
    __builtin_amdgcn_s_barrier();
    mfmaQ(0, 2, 1);
    __builtin_amdgcn_s_barrier();
    // p2
    loadA4(Ab0, 4);
    stageB1(ka, 1);
    __builtin_amdgcn_s_barrier();
    mfmaQ(4, 2, 1);
    __builtin_amdgcn_s_barrier();
    // p3 (no ds_reads -> MFMA starts with zero lgkm drain)
    if (st) stageA(kb, 0, 0);
    __builtin_amdgcn_s_barrier();
    mfmaQ(4, 0, 2);
    if (st) { asm volatile("s_waitcnt vmcnt(2)" ::: "memory"); }
    else    { asm volatile("s_waitcnt vmcnt(0)" ::: "memory"); }
    __builtin_amdgcn_s_barrier();

    // ---- K-tile 2t+1 from buf1 ----
    // p4
    loadA4(Ab1, 0); loadB(Bb1, 0, 2);
    if (st) stageA(kb, 0, 1);
    __builtin_amdgcn_s_barrier();
    mfmaQ(0, 0, 2);
    __builtin_amdgcn_s_barrier();
    // p5
    loadB(Bb1, 2, 1);
    if (st) stageB0(kb, 0);
    __builtin_amdgcn_s_barrier();
    mfmaQ(0, 2, 1);
    __builtin_amdgcn_s_barrier();
    // p6
    loadA4(Ab1, 4);
    if (st) stageB1(kb, 0);
    __builtin_amdgcn_s_barrier();
    mfmaQ(4, 2, 1);
    __builtin_amdgcn_s_barrier();
    // p7 (no ds_reads)
    if (st) stageA(kc, 1, 0);
    __builtin_amdgcn_s_barrier();
    mfmaQ(4, 0, 2);
    if (st) { asm volatile("s_waitcnt vmcnt(2)" ::: "memory"); }
    __builtin_amdgcn_s_barrier();
  }

  // ---- epilogue ----
  __syncthreads();
  const int bI  = m0 >> 11;
  const int s0m = m0 & 2047;
  // vs0 = first V-range local column (192 = none, 0 = all V; multiple of 64)
  const int vs0 = (n0 >= 2048) ? 0 : ((n0 + 192 <= 2048) ? 192 : (2048 - n0));

  // pass 1: Q/K columns -> row-major LDS [256][200] -> [BH][S][DH] stores
  if (vs0 > 0) {
#pragma unroll
    for (int j = 0; j < 3; j++) {
      const int cl = wn + j * 16 + fr;
      if (cl < vs0) {
        const int ncol = n0 + cl;
        const int which = ncol >> 10;             // 0 or 1 here
        const float bb = ((which == 0) ? b0 : b1)[ncol & 1023];
        const float post = (which == 0) ? 0.18033688011f : 1.0f;  // 0.125*log2(e)
#pragma unroll
        for (int i = 0; i < 8; i++) {
#pragma unroll
          for (int r = 0; r < 4; r++) {
            const int row = wm + i * 16 + g * 4 + r;
            lds[row * 200 + cl] = f2bf((acc[i][j][r] + bb) * post);
          }
        }
      }
    }
    __syncthreads();
    const int part = tid & 7;
#pragma unroll
    for (int p = 0; p < 12; p++) {
      const int hc = p >> 2;
      if (hc * 64 < vs0) {                        // chunk fully Q/K
        const int ml = ((p & 3) << 6) + (tid >> 3);
        const int ncol0 = n0 + hc * 64;
        const int which = ncol0 >> 10;
        const int h = (ncol0 >> 6) & 15;
        const bf16x8 v = *(const bf16x8*)(lds + ml * 200 + hc * 64 + part * 8);
        *(bf16x8*)(qkv_out + (size_t)which * 8388608 +
                   ((size_t)(bI * 16 + h) * 2048 + s0m + ml) * 64 + part * 8) = v;
      }
    }
  }

  // pass 2: V columns -> col-major LDS [clv][264] -> coalesced V^T [BH][DH][S]
  if (vs0 < 192) {
    __syncthreads();                              // pass-1 LDS reads drained
#pragma unroll
    for (int j = 0; j < 3; j++) {
      const int cl = wn + j * 16 + fr;
      const int clv = cl - vs0;
      if (clv >= 0) {
        const int ncol = n0 + cl;
        const float bb = b2[ncol & 1023];
#pragma unroll
        for (int i = 0; i < 8; i++) {
#pragma unroll
          for (int r = 0; r < 4; r++) {
            const int row = wm + i * 16 + g * 4 + r;
            lds[clv * 264 + row] = f2bf(acc[i][j][r] + bb);
          }
        }
      }
    }
    __syncthreads();
    const int vcols = 192 - vs0;
    const int mg = tid & 31;                      // s-group: lanes contiguous in s
    const int cidx = tid >> 5;                    // 0..15
    for (int cc = cidx; cc < vcols; cc += 16) {
      const int ncol = n0 + vs0 + cc;
      const int h = (ncol >> 6) & 15;
      const int dh = ncol & 63;
      const bf16x8 v = *(const bf16x8*)(lds + cc * 264 + mg * 8);
      *(bf16x8*)(vT_out + ((size_t)(bI * 16 + h) * 64 + dh) * 2048 + s0m + mg * 8) = v;
    }
  }
}

// ---------------- 256x128 6-phase output GEMM: out = attn * Wo^T + bo (fp32) ----------------
__global__ __launch_bounds__(512) void gemm_o_256(
    const u16* __restrict__ A, const u16* __restrict__ Bw,
    const float* __restrict__ bo, float* __restrict__ out)
{
  __shared__ u16 lds[49152];   // 96 KiB

  const int tid = threadIdx.x;
  const int lane = tid & 63;
  const int wave = tid >> 6;

  const int bid = (int)blockIdx.x;
  const int xcd = bid & 7;
  const int idx = bid >> 3;                 // 0..31
  const int mt = (xcd << 2) | (idx & 3);    // 0..31
  const int nt = idx >> 2;                  // 0..7
  const int m0 = mt << 8;
  const int n0 = nt << 7;

  const int warp_m = wave >> 2;
  const int warp_n = wave & 3;
  const int wm = warp_m << 7;
  const int wn = warp_n << 5;               // 0,32,64,96
  const int fr = lane & 15;
  const int g  = lane >> 4;

  const int srow = tid >> 3;
  const int schk = ((tid & 7) ^ (srow & 7)) << 3;
  const u16* pA = A  + (size_t)(m0 + srow) * 1024 + schk;
  const u16* pB = Bw + (size_t)(n0 + srow) * 1024 + schk;

  const int rsw0 = ((g    ) ^ (fr & 7)) << 3;
  const int rsw1 = ((g ^ 4) ^ (fr & 7)) << 3;

  const u16* Ab0 = lds + (size_t)(wm + fr) * 64;
  const u16* Bb0 = lds + 16384 + (size_t)(wn + fr) * 64;
  const u16* Ab1 = Ab0 + 24576;
  const u16* Bb1 = Bb0 + 24576;

  f32x4 acc[8][2];
  const f32x4 zero = {0.f, 0.f, 0.f, 0.f};
#pragma unroll
  for (int i = 0; i < 8; i++)
#pragma unroll
    for (int j = 0; j < 2; j++) acc[i][j] = zero;

  bf16x8 a_[8][2];
  bf16x8 b_[2][2];

  auto stageA = [&](int kt, int buf, int half) {   // 2 loads (128 rows)
    const u16* src = pA + (size_t)half * 131072 + (kt << 6);
    u16* dst = lds + buf * 24576 + half * 8192 + tid * 8;
    llds16(src, dst);
    llds16(src + 65536, dst + 4096);
  };
  auto stageB = [&](int kt, int buf) {             // 2 loads (128 rows)
    const u16* src = pB + (kt << 6);
    u16* dst = lds + buf * 24576 + 16384 + tid * 8;
    llds16(src, dst);
    llds16(src + 65536, dst + 4096);
  };
  auto loadA4 = [&](const u16* Ab, int ib) {
#pragma unroll
    for (int ii = 0; ii < 4; ii++) {
      const u16* r = Ab + (ib + ii) * 1024;
      a_[ib + ii][0] = *(const bf16x8*)(r + rsw0);
      a_[ib + ii][1] = *(const bf16x8*)(r + rsw1);
    }
  };
  auto loadB2 = [&](const u16* Bb) {
#pragma unroll
    for (int jj = 0; jj < 2; jj++) {
      const u16* r = Bb + jj * 1024;
      b_[jj][0] = *(const bf16x8*)(r + rsw0);
      b_[jj][1] = *(const bf16x8*)(r + rsw1);
    }
  };
  auto mfma16 = [&](int ib) {
    __builtin_amdgcn_s_setprio(1);
#pragma unroll
    for (int jj = 0; jj < 2; jj++)
#pragma unroll
      for (int ii = 0; ii < 4; ii++) {
        acc[ib+ii][jj] = __builtin_amdgcn_mfma_f32_16x16x32_bf16(
            a_[ib+ii][0], b_[jj][0], acc[ib+ii][jj], 0, 0, 0);
        acc[ib+ii][jj] = __builtin_amdgcn_mfma_f32_16x16x32_bf16(
            a_[ib+ii][1], b_[jj][1], acc[ib+ii][jj], 0, 0, 0);
      }
    __builtin_amdgcn_s_setprio(0);
  };
  auto mfma8 = [&](int ib, int jj) {
    __builtin_amdgcn_s_setprio(1);
#pragma unroll
    for (int ii = 0; ii < 4; ii++) {
      acc[ib+ii][jj] = __builtin_amdgcn_mfma_f32_16x16x32_bf16(
          a_[ib+ii][0], b_[jj][0], acc[ib+ii][jj], 0, 0, 0);
      acc[ib+ii][jj] = __builtin_amdgcn_mfma_f32_16x16x32_bf16(
          a_[ib+ii][1], b_[jj][1], acc[ib+ii][jj], 0, 0, 0);
    }
    __builtin_amdgcn_s_setprio(0);
  };

  // prologue: buf0 <- K-tile 0 (A0,A1,B = 6 loads), buf1.A0 <- K-tile 1 (2)
  stageA(0, 0, 0);
  stageA(0, 0, 1);
  stageB(0, 0);
  stageA(1, 1, 0);
  asm volatile("s_waitcnt vmcnt(2)" ::: "memory");
  __builtin_amdgcn_s_barrier();

  const int NTI = 8;   // K / 128
  for (int t = 0; t < NTI; ++t) {
    const bool st = (t < NTI - 1);
    const int ka = 2 * t + 1;
    const int kb = 2 * t + 2;
    const int kc = 2 * t + 3;

    // ---- K-tile 2t from buf0 ----
    loadA4(Ab0, 0); loadB2(Bb0);
    stageA(ka, 1, 1);
    __builtin_amdgcn_s_barrier();
    mfma16(0);
    __builtin_amdgcn_s_barrier();
    loadA4(Ab0, 4);
    stageB(ka, 1);
    __builtin_amdgcn_s_barrier();
    mfma8(4, 0);
    __builtin_amdgcn_s_barrier();
    if (st) stageA(kb, 0, 0);
    __builtin_amdgcn_s_barrier();
    mfma8(4, 1);
    if (st) { asm volatile("s_waitcnt vmcnt(2)" ::: "memory"); }
    else    { asm volatile("s_waitcnt vmcnt(0)" ::: "memory"); }
    __builtin_amdgcn_s_barrier();

    // ---- K-tile 2t+1 from buf1 ----
    loadA4(Ab1, 0); loadB2(Bb1);
    if (st) stageA(kb, 0, 1);
    __builtin_amdgcn_s_barrier();
    mfma16(0);
    __builtin_amdgcn_s_barrier();
    loadA4(Ab1, 4);
    if (st) stageB(kb, 0);
    __builtin_amdgcn_s_barrier();
    mfma8(4, 0);
    __builtin_amdgcn_s_barrier();
    if (st) stageA(kc, 1, 0);
    __builtin_amdgcn_s_barrier();
    mfma8(4, 1);
    if (st) { asm volatile("s_waitcnt vmcnt(2)" ::: "memory"); }
    __builtin_amdgcn_s_barrier();
  }

  // epilogue: fp32 direct stores with bias
#pragma unroll
  for (int j = 0; j < 2; j++) {
    const int n = n0 + wn + j * 16 + fr;
    const float bb = bo[n];
#pragma unroll
    for (int i = 0; i < 8; i++) {
#pragma unroll
      for (int r = 0; r < 4; r++) {
        const int m = m0 + wm + i * 16 + g * 4 + r;
        out[(size_t)m * 1024 + n] = acc[i][j][r] + bb;
      }
    }
  }
}

// ---------------- MFMA flash attention: single q-tile, PV deferred, 3 blocks/CU ----------------
// Round-9 proven loop.  qt-priority ladder; O-epilogue restaged through the
// dead p_s buffer (wave-private rows, in-order LDS -> no barrier) for
// 16B/lane coalesced stores instead of 32x 2B scalar stores per lane.
__global__ __launch_bounds__(256, 3) void attn_fa(
    const u16* __restrict__ Qb, const u16* __restrict__ Kb,
    const u16* __restrict__ VT, u16* __restrict__ Ob)
{
  __shared__ u16 k_s[2 * 4096];      // dbuf [kn][d], 16B-chunks XOR'd by row
  __shared__ u16 v_s[2 * 4096];      // dbuf [dn][k], same swizzle (lags K by 1 tile)
  __shared__ u16 p_s[128 * 72];      // [q][key] bf16, stride 72 (wave-private rows)
  __shared__ float l_s[128];

  const int tid = threadIdx.x;
  const int lane = tid & 63;
  const int wave = tid >> 6;
  const int bid = (int)blockIdx.x;
  const int qt = 15 - (bid >> 6);               // big tiles first
  const int bh = (((bid >> 3) & 7) << 3) | (bid & 7);   // bh % 8 == bid % 8 (XCD)
  const size_t head = (size_t)bh << 17;
  const int fr = lane & 15;
  const int g = lane >> 4;
  const int k8 = g << 3;
  const int q0 = qt << 7;
  const int wrow = wave << 5;

  // critical-path priority ladder (wave-uniform; persists for the kernel)
  if (qt >= 14)     __builtin_amdgcn_s_setprio(2);
  else if (qt >= 8) __builtin_amdgcn_s_setprio(1);

  // Q fragments (pre-scaled); loop-invariant B-operands
  bf16x8 aq[2][2];
#pragma unroll
  for (int f = 0; f < 2; f++) {
    const u16* qp = Qb + head + (size_t)(q0 + wrow + (f << 4) + fr) * 64;
    aq[f][0] = *(const bf16x8*)(qp + k8);
    aq[f][1] = *(const bf16x8*)(qp + 32 + k8);
  }

  // ---- hoisted lane-constant offsets ----
  const int r0 = tid >> 3, c0 = tid & 7;
  const int r1 = 32 + r0;
  const int koff0 = r0 * 64 + (((c0 ^ r0) & 7) << 3);     // K staging src offsets
  const int koff1 = r1 * 64 + (((c0 ^ r1) & 7) << 3);
  const int voff0 = r0 * 2048 + (((c0 ^ r0) & 7) << 3);   // V^T staging src offsets
  const int voff1 = r1 * 2048 + (((c0 ^ r1) & 7) << 3);
  int kaddr[4][2], vaddr[2][4];                           // fragment-read offsets
#pragma unroll
  for (int j = 0; j < 4; j++) {
    const int kn = (j << 4) + fr;
    kaddr[j][0] = kn * 64 + (((g ^ kn) & 7) << 3);
    kaddr[j][1] = kn * 64 + ((((g + 4) ^ kn) & 7) << 3);
#pragma unroll
    for (int s2 = 0; s2 < 2; s2++)
      vaddr[s2][j] = kn * 64 + ((((s2 << 2) + g) ^ (kn & 7)) << 3);
  }
  u16* const prow0 = p_s + (wrow + fr) * 72;        // q row f=0 (write cols & read k8)
  u16* const prow1 = p_s + (wrow + 16 + fr) * 72;   // q row f=1
  const u16* Kbase = Kb + head;
  const u16* Vbase = VT + head;

  auto issueK = [&](int jt2, int buf) {
    const u16* Kt = Kbase + ((size_t)jt2 << 12);
    llds16(Kt + koff0, k_s + (buf << 12) + tid * 8);
    llds16(Kt + koff1, k_s + (buf << 12) + 2048 + tid * 8);
  };
  auto issueV = [&](int jt2, int buf) {
    const u16* Vt = Vbase + (jt2 << 6);
    llds16(Vt + voff0, v_s + (buf << 12) + tid * 8);
    llds16(Vt + voff1, v_s + (buf << 12) + 2048 + tid * 8);
  };

  f32x4 o_acc[2][4];
  const f32x4 zero = {0.f, 0.f, 0.f, 0.f};
#pragma unroll
  for (int f = 0; f < 2; f++)
#pragma unroll
    for (int j = 0; j < 4; j++) o_acc[f][j] = zero;
  float l_run[2] = {0.f, 0.f};

  const int jmax = 2 * qt + 1;                 // jmax+1 iterations (even count)
  const int jt_diag = 2 * qt + (wave >> 1);    // per-wave diagonal tile

  auto do_pv = [&](const u16* vs) {
#pragma unroll
    for (int s2 = 0; s2 < 2; s2++) {
      const bf16x8 ap0 = *(const bf16x8*)(prow0 + (s2 << 5) + k8);
      const bf16x8 ap1 = *(const bf16x8*)(prow1 + (s2 << 5) + k8);
#pragma unroll
      for (int j = 0; j < 4; j++) {
        const bf16x8 bv = *(const bf16x8*)(vs + vaddr[s2][j]);
        o_acc[0][j] = __builtin_amdgcn_mfma_f32_16x16x32_bf16(ap0, bv, o_acc[0][j], 0, 0, 0);
        o_acc[1][j] = __builtin_amdgcn_mfma_f32_16x16x32_bf16(ap1, bv, o_acc[1][j], 0, 0, 0);
      }
    }
  };

  auto do_s = [&](const u16* ks, bool dodiag, int jt) {
    f32x4 s_acc[2][4];
#pragma unroll
    for (int f = 0; f < 2; f++)
#pragma unroll
      for (int j = 0; j < 4; j++) s_acc[f][j] = zero;
#pragma unroll
    for (int j = 0; j < 4; j++) {
      const bf16x8 ka0 = *(const bf16x8*)(ks + kaddr[j][0]);
      const bf16x8 ka1 = *(const bf16x8*)(ks + kaddr[j][1]);
      s_acc[0][j] = __builtin_amdgcn_mfma_f32_16x16x32_bf16(ka0, aq[0][0], s_acc[0][j], 0, 0, 0);
      s_acc[0][j] = __builtin_amdgcn_mfma_f32_16x16x32_bf16(ka1, aq[0][1], s_acc[0][j], 0, 0, 0);
      s_acc[1][j] = __builtin_amdgcn_mfma_f32_16x16x32_bf16(ka0, aq[1][0], s_acc[1][j], 0, 0, 0);
      s_acc[1][j] = __builtin_amdgcn_mfma_f32_16x16x32_bf16(ka1, aq[1][1], s_acc[1][j], 0, 0, 0);
    }
#pragma unroll
    for (int f = 0; f < 2; f++) {
      const int qa = q0 + wrow + (f << 4) + fr;
      u16* prow = (f == 0) ? prow0 : prow1;
      if (dodiag) {
#pragma unroll
        for (int j = 0; j < 4; j++) {
          const int kb = (jt << 6) + (j << 4) + (g << 2);
          float p0 = (kb + 0 > qa) ? 0.f : __builtin_amdgcn_exp2f(s_acc[f][j][0]);
          float p1 = (kb + 1 > qa) ? 0.f : __builtin_amdgcn_exp2f(s_acc[f][j][1]);
          float p2 = (kb + 2 > qa) ? 0.f : __builtin_amdgcn_exp2f(s_acc[f][j][2]);
          float p3 = (kb + 3 > qa) ? 0.f : __builtin_amdgcn_exp2f(s_acc[f][j][3]);
          l_run[f] += (p0 + p1) + (p2 + p3);
          union { __hip_bfloat162 h; unsigned u; } ca, cb;
          ca.h = __float22bfloat162_rn(make_float2(p0, p1));
          cb.h = __float22bfloat162_rn(make_float2(p2, p3));
          *(uint2*)(prow + (j << 4) + (g << 2)) = make_uint2(ca.u, cb.u);
        }
      } else {
#pragma unroll
        for (int j = 0; j < 4; j++) {
          float p0 = __builtin_amdgcn_exp2f(s_acc[f][j][0]);
          float p1 = __builtin_amdgcn_exp2f(s_acc[f][j][1]);
          float p2 = __builtin_amdgcn_exp2f(s_acc[f][j][2]);
          float p3 = __builtin_amdgcn_exp2f(s_acc[f][j][3]);
          l_run[f] += (p0 + p1) + (p2 + p3);
          union { __hip_bfloat162 h; unsigned u; } ca, cb;
          ca.h = __float22bfloat162_rn(make_float2(p0, p1));
          cb.h = __float22bfloat162_rn(make_float2(p2, p3));
          *(uint2*)(prow + (j << 4) + (g << 2)) = make_uint2(ca.u, cb.u);
        }
      }
    }
  };

  issueK(0, 0);   // prime K pipeline (V(0) issued inside iteration 0)

  for (int jt = 0; jt <= jmax; jt++) {
    const int kb = jt & 1;
    __syncthreads();                       // K(jt) + V(jt-1) landed; LDS reads drained
    if (jt < jmax) issueK(jt + 1, kb ^ 1);
    issueV(jt, kb);
    if (jt > 0 && jt - 1 <= jt_diag) do_pv(v_s + ((kb ^ 1) << 12));   // deferred PV
    if (jt <= jt_diag) do_s(k_s + (kb << 12), jt == jt_diag, jt);
  }
  __syncthreads();                         // V(jmax) landed
  if (jt_diag == jmax) do_pv(v_s + ((jmax & 1) << 12));   // waves 2,3 final PV

  // ---- epilogue (all wave-private; no barriers needed) ----
  // reduce l (q-col lives in lanes fr, fr+16, fr+32, fr+48)
#pragma unroll
  for (int f = 0; f < 2; f++) {
    float l = l_run[f];
    l += __shfl_xor(l, 16);
    l += __shfl_xor(l, 32);
    if (g == 0) l_s[wrow + (f << 4) + fr] = l;   // wave-private slot
  }
  // scale + restage O through p_s (this wave's rows; dead after final do_pv)
#pragma unroll
  for (int f = 0; f < 2; f++) {
#pragma unroll
    for (int r = 0; r < 4; r++) {
      const int qloc = wrow + (f << 4) + (g << 2) + r;
      const float inv = 1.f / l_s[qloc];
#pragma unroll
      for (int j = 0; j < 4; j++)
        p_s[qloc * 72 + (j << 4) + fr] = f2bf(o_acc[f][j][r] * inv);
    }
  }
  // coalesced store: wave's 32 rows x 64 cols, 16B/lane (32B contiguous per row-pair)
  const int b = bh >> 4, h = bh & 15;
  const int rowl = wrow + (lane >> 1);
  const int colh = (lane & 1) << 3;
  u16* const obase = Ob + ((size_t)b * 2048 + q0 + rowl) * 1024 + (h << 6);
#pragma unroll
  for (int k = 0; k < 4; k++) {
    const int c0 = (k << 4) + colh;
    const bf16x8 v = *(const bf16x8*)(p_s + rowl * 72 + c0);
    *(bf16x8*)(obase + c0) = v;
  }
}

// ---------------- launch ----------------
extern "C" void kernel_launch(void* const* d_in, const int* in_sizes, int n_in,
                              void* d_out, int out_size, void* d_ws, size_t ws_size,
                              hipStream_t stream) {
  const float* x  = (const float*)d_in[0];
  const float* Wq = (const float*)d_in[1];
  const float* bq = (const float*)d_in[2];
  const float* Wk = (const float*)d_in[3];
  const float* bk = (const float*)d_in[4];
  const float* Wv = (const float*)d_in[5];
  const float* bv = (const float*)d_in[6];
  const float* Wo = (const float*)d_in[7];
  const float* bo = (const float*)d_in[8];
  float* out = (float*)d_out;

  char* ws = (char*)d_ws;
  u16* xb    = (u16*)(ws);                 // 16 MB; dead after QKV GEMM
  u16* attnb = (u16*)(ws);                 // aliases xb (dead by then)
  u16* wqkv  = (u16*)(ws + 16777216);      // 6 MB packed q|k|v weights
  u16* wo    = (u16*)(ws + 23068672);      // 2 MB
  u16* qkv   = (u16*)(ws + 25165824);      // 32 MB: Q | K  [BH][S][DH]
  u16* vT    = (u16*)(ws + 58720256);      // 16 MB: V^T [BH][64][S]
  // total ws: 75,497,472 B

  // fused cast: x + all 4 weight matrices, one launch
  cast_all_kernel<<<12288, 256, 0, stream>>>(x, Wq, Wk, Wv, Wo, xb, wqkv, wo);

  // fused QKV projection + V-transpose: M=8192, N=3072, K=1024
  gemm_qkv_256<<<dim3(512), 512, 0, stream>>>(xb, wqkv, bq, bk, bv, qkv, vT);

  // MFMA flash attention (single q-tile/block, big-first dispatch, 3 blocks/CU,
  // qt-priority ladder, coalesced O-epilogue); writes attnb over dead xb
  attn_fa<<<dim3(1024), 256, 0, stream>>>(qkv, qkv + 8388608, vT, attnb);

  // output projection: M=8192, N=1024, K=1024 (256x128 6-phase, 1 clean round)
  gemm_o_256<<<dim3(256), 512, 0, stream>>>(attnb, wo, bo, out);
}

// Round 13
// 233.036 us; speedup vs baseline: 1.0086x; 1.0086x over previous
//
#include <hip/hip_runtime.h>
#include <hip/hip_bf16.h>
#include <cstdint>
#include <cstddef>

// B=4, S=2048, D=1024, H=16, DH=64.  M = B*S = 8192.
// fused cast (x + 4 weights); fused QKV GEMM (256x192 8-phase, counted-vmcnt,
// fused V-transpose epilogue); MFMA flash attention (single q-tile, dbuf K/V
// + __syncthreads loop, 3 blocks/CU, big-first dispatch, qt-priority ladder,
// coalesced O-epilogue via p_s restage); output GEMM (256x128 6-phase,
// 1 clean round) with LDS-restaged fp32 epilogue: C staged per 128-row half
// as [128][132] fp32 (+bias) then stored as float4/lane covering contiguous
// 512B rows -- replaces per-lane scalar 4B stores on 32 MB of output.
// Workspace 75,497,472 B: xb/attnb 16M | wqkv 6M | wo 2M | Q,K 32M | vT 16M.

typedef unsigned short u16;
typedef __bf16 bf16x8 __attribute__((ext_vector_type(8)));
typedef float  f32x4  __attribute__((ext_vector_type(4)));

__device__ __forceinline__ u16 f2bf(float f) {
  unsigned u = __float_as_uint(f);
  unsigned r = u + 0x7fffu + ((u >> 16) & 1u);   // RNE
  return (u16)(r >> 16);
}

// async global->LDS, 16B per lane (dest = wave-uniform base + lane*16)
__device__ __forceinline__ void llds16(const u16* g, u16* l) {
  __builtin_amdgcn_global_load_lds(
      (const __attribute__((address_space(1))) void*)g,
      (__attribute__((address_space(3))) void*)l, 16, 0, 0);
}

// ---------------- fused cast fp32 -> bf16 (x + Wq,Wk,Wv,Wo) ----------------
__global__ void cast_all_kernel(const float* __restrict__ x,
                                const float* __restrict__ Wq, const float* __restrict__ Wk,
                                const float* __restrict__ Wv, const float* __restrict__ Wo,
                                u16* __restrict__ xb, u16* __restrict__ wqkv,
                                u16* __restrict__ wo) {
  const int bid = (int)blockIdx.x;
  const int tid = threadIdx.x;
  if (bid < 8192) {
    const int i = (bid << 8) + tid;
    float4 f = ((const float4*)x)[i];
    ushort4 u;
    u.x = f2bf(f.x); u.y = f2bf(f.y); u.z = f2bf(f.z); u.w = f2bf(f.w);
    ((ushort4*)xb)[i] = u;
  } else {
    const int j = ((bid - 8192) << 8) + tid;   // 0..1048575
    const int w = j >> 18;                     // 0..3
    const int idx = j & 262143;
    const float* src = (w == 0) ? Wq : (w == 1) ? Wk : (w == 2) ? Wv : Wo;
    u16* dst = (w == 3) ? wo : (wqkv + (w << 20));
    float4 f = ((const float4*)src)[idx];
    ushort4 u;
    u.x = f2bf(f.x); u.y = f2bf(f.y); u.z = f2bf(f.z); u.w = f2bf(f.w);
    ((ushort4*)dst)[idx] = u;
  }
}

// ---------------- 256x192 8-phase QKV GEMM + fused V-transpose ----------------
__global__ __launch_bounds__(512) void gemm_qkv_256(
    const u16* __restrict__ A, const u16* __restrict__ Bw,
    const float* __restrict__ b0, const float* __restrict__ b1, const float* __restrict__ b2,
    u16* __restrict__ qkv_out, u16* __restrict__ vT_out)
{
  __shared__ u16 lds[57344];   // 112 KiB (reused as epilogue staging)

  const int tid = threadIdx.x;
  const int lane = tid & 63;
  const int wave = tid >> 6;

  // XCD-grouped decode: xcd = bid&7; each XCD owns 4 m-panels x all 16 n-tiles.
  const int bid = (int)blockIdx.x;
  const int xcd = bid & 7;
  const int idx = bid >> 3;                 // 0..63
  const int mt = (xcd << 2) | (idx & 3);    // 0..31
  const int nt = idx >> 2;                  // 0..15
  const int m0 = mt << 8;
  const int n0 = nt * 192;

  const int warp_m = wave >> 2;       // 0..1
  const int warp_n = wave & 3;        // 0..3
  const int wm = warp_m << 7;         // 0,128
  const int wn = warp_n * 48;         // 0,48,96,144
  const int fr = lane & 15;
  const int g  = lane >> 4;           // 0..3

  // staging source (pre-swizzled global addr so linear LDS dest lands swizzled)
  const int srow = tid >> 3;                       // 0..63
  const int schk = ((tid & 7) ^ (srow & 7)) << 3;  // stored chunk -> logical col
  const u16* pA = A  + (size_t)(m0 + srow) * 1024 + schk;
  const u16* pB = Bw + (size_t)(n0 + srow) * 1024 + schk;

  // fragment-read swizzled chunk offsets (chunk = s*4+g, stored = chunk^(row&7))
  const int rsw0 = ((g    ) ^ (fr & 7)) << 3;
  const int rsw1 = ((g ^ 4) ^ (fr & 7)) << 3;

  // read bases (include fr*64 row offset); buf stride 28672 u16
  const u16* Ab0 = lds + (size_t)(wm + fr) * 64;
  const u16* Bb0 = lds + 16384 + (size_t)(wn + fr) * 64;
  const u16* Ab1 = Ab0 + 28672;
  const u16* Bb1 = Bb0 + 28672;

  f32x4 acc[8][3];
  const f32x4 zero = {0.f, 0.f, 0.f, 0.f};
#pragma unroll
  for (int i = 0; i < 8; i++)
#pragma unroll
    for (int j = 0; j < 3; j++) acc[i][j] = zero;

  bf16x8 a_[4][2];
  bf16x8 b_[3][2];

  auto stageA = [&](int kt, int buf, int half) {   // 2 loads (128 rows)
    const u16* src = pA + (size_t)half * 131072 + (kt << 6);
    u16* dst = lds + buf * 28672 + half * 8192 + tid * 8;
    llds16(src, dst);
    llds16(src + 65536, dst + 4096);
  };
  auto stageB0 = [&](int kt, int buf) {            // 2 loads (rows 0-127)
    const u16* src = pB + (kt << 6);
    u16* dst = lds + buf * 28672 + 16384 + tid * 8;
    llds16(src, dst);
    llds16(src + 65536, dst + 4096);
  };
  auto stageB1 = [&](int kt, int buf) {            // 1 load (rows 128-191)
    const u16* src = pB + 131072 + (kt << 6);
    u16* dst = lds + buf * 28672 + 24576 + tid * 8;
    llds16(src, dst);
  };
  auto loadA4 = [&](const u16* Ab, int ib) {
#pragma unroll
    for (int ii = 0; ii < 4; ii++) {
      const u16* r = Ab + (ib + ii) * 1024;
      a_[ii][0] = *(const bf16x8*)(r + rsw0);
      a_[ii][1] = *(const bf16x8*)(r + rsw1);
    }
  };
  auto loadB = [&](const u16* Bb, int j0, int nj) {
#pragma unroll
    for (int jj = 0; jj < 3; jj++) {
      if (jj < nj) {
        const u16* r = Bb + (j0 + jj) * 1024;
        b_[j0 + jj][0] = *(const bf16x8*)(r + rsw0);
        b_[j0 + jj][1] = *(const bf16x8*)(r + rsw1);
      }
    }
  };
  auto mfmaQ = [&](int ib, int j0, int nj) {
    __builtin_amdgcn_s_setprio(1);
#pragma unroll
    for (int jj = 0; jj < 3; jj++) {
      if (jj < nj) {
#pragma unroll
        for (int ii = 0; ii < 4; ii++) {
          acc[ib+ii][j0+jj] = __builtin_amdgcn_mfma_f32_16x16x32_bf16(
              a_[ii][0], b_[j0+jj][0], acc[ib+ii][j0+jj], 0, 0, 0);
          acc[ib+ii][j0+jj] = __builtin_amdgcn_mfma_f32_16x16x32_bf16(
              a_[ii][1], b_[j0+jj][1], acc[ib+ii][j0+jj], 0, 0, 0);
        }
      }
    }
    __builtin_amdgcn_s_setprio(0);
  };

  // prologue: buf0 <- K-tile 0 (A0,A1,B0,B1 = 7 loads), buf1.A0 <- K-tile 1 (2)
  stageA(0, 0, 0);
  stageA(0, 0, 1);
  stageB0(0, 0);
  stageB1(0, 0);
  stageA(1, 1, 0);
  asm volatile("s_waitcnt vmcnt(2)" ::: "memory");  // tile0 landed; tile1.A0 in flight
  __builtin_amdgcn_s_barrier();

  const int NTI = 8;   // K / 128
  for (int t = 0; t < NTI; ++t) {
    const bool st = (t < NTI - 1);
    const int ka = 2 * t + 1;
    const int kb = 2 * t + 2;
    const int kc = 2 * t + 3;

    // ---- K-tile 2t from buf0 ----
    // p0
    loadA4(Ab0, 0); loadB(Bb0, 0, 2);
    stageA(ka, 1, 1);
    __builtin_amdgcn_s_barrier();
    mfmaQ(0, 0, 2);
    __builtin_amdgcn_s_barrier();
    // p1
    loadB(Bb0, 2, 1);
    stageB0(ka, 1);
    __builtin_amdgcn_s_barrier();
    mfmaQ(0, 2, 1);
    __builtin_amdgcn_s_barrier();
    // p2
    loadA4(Ab0, 4);
    stageB1(ka, 1);
    __builtin_amdgcn_s_barrier();
    mfmaQ(4, 2, 1);
    __builtin_amdgcn_s_barrier();
    // p3 (no ds_reads -> MFMA starts with zero lgkm drain)
    if (st) stageA(kb, 0, 0);
    __builtin_amdgcn_s_barrier();
    mfmaQ(4, 0, 2);
    if (st) { asm volatile("s_waitcnt vmcnt(2)" ::: "memory"); }
    else    { asm volatile("s_waitcnt vmcnt(0)" ::: "memory"); }
    __builtin_amdgcn_s_barrier();

    // ---- K-tile 2t+1 from buf1 ----
    // p4
    loadA4(Ab1, 0); loadB(Bb1, 0, 2);
    if (st) stageA(kb, 0, 1);
    __builtin_amdgcn_s_barrier();
    mfmaQ(0, 0, 2);
    __builtin_amdgcn_s_barrier();
    // p5
    loadB(Bb1, 2, 1);
    if (st) stageB0(kb, 0);
    __builtin_amdgcn_s_barrier();
    mfmaQ(0, 2, 1);
    __builtin_amdgcn_s_barrier();
    // p6
    loadA4(Ab1, 4);
    if (st) stageB1(kb, 0);
    __builtin_amdgcn_s_barrier();
    mfmaQ(4, 2, 1);
    __builtin_amdgcn_s_barrier();
    // p7 (no ds_reads)
    if (st) stageA(kc, 1, 0);
    __builtin_amdgcn_s_barrier();
    mfmaQ(4, 0, 2);
    if (st) { asm volatile("s_waitcnt vmcnt(2)" ::: "memory"); }
    __builtin_amdgcn_s_barrier();
  }

  // ---- epilogue ----
  __syncthreads();
  const int bI  = m0 >> 11;
  const int s0m = m0 & 2047;
  // vs0 = first V-range local column (192 = none, 0 = all V; multiple of 64)
  const int vs0 = (n0 >= 2048) ? 0 : ((n0 + 192 <= 2048) ? 192 : (2048 - n0));

  // pass 1: Q/K columns -> row-major LDS [256][200] -> [BH][S][DH] stores
  if (vs0 > 0) {
#pragma unroll
    for (int j = 0; j < 3; j++) {
      const int cl = wn + j * 16 + fr;
      if (cl < vs0) {
        const int ncol = n0 + cl;
        const int which = ncol >> 10;             // 0 or 1 here
        const float bb = ((which == 0) ? b0 : b1)[ncol & 1023];
        const float post = (which == 0) ? 0.18033688011f : 1.0f;  // 0.125*log2(e)
#pragma unroll
        for (int i = 0; i < 8; i++) {
#pragma unroll
          for (int r = 0; r < 4; r++) {
            const int row = wm + i * 16 + g * 4 + r;
            lds[row * 200 + cl] = f2bf((acc[i][j][r] + bb) * post);
          }
        }
      }
    }
    __syncthreads();
    const int part = tid & 7;
#pragma unroll
    for (int p = 0; p < 12; p++) {
      const int hc = p >> 2;
      if (hc * 64 < vs0) {                        // chunk fully Q/K
        const int ml = ((p & 3) << 6) + (tid >> 3);
        const int ncol0 = n0 + hc * 64;
        const int which = ncol0 >> 10;
        const int h = (ncol0 >> 6) & 15;
        const bf16x8 v = *(const bf16x8*)(lds + ml * 200 + hc * 64 + part * 8);
        *(bf16x8*)(qkv_out + (size_t)which * 8388608 +
                   ((size_t)(bI * 16 + h) * 2048 + s0m + ml) * 64 + part * 8) = v;
      }
    }
  }

  // pass 2: V columns -> col-major LDS [clv][264] -> coalesced V^T [BH][DH][S]
  if (vs0 < 192) {
    __syncthreads();                              // pass-1 LDS reads drained
#pragma unroll
    for (int j = 0; j < 3; j++) {
      const int cl = wn + j * 16 + fr;
      const int clv = cl - vs0;
      if (clv >= 0) {
        const int ncol = n0 + cl;
        const float bb = b2[ncol & 1023];
#pragma unroll
        for (int i = 0; i < 8; i++) {
#pragma unroll
          for (int r = 0; r < 4; r++) {
            const int row = wm + i * 16 + g * 4 + r;
            lds[clv * 264 + row] = f2bf(acc[i][j][r] + bb);
          }
        }
      }
    }
    __syncthreads();
    const int vcols = 192 - vs0;
    const int mg = tid & 31;                      // s-group: lanes contiguous in s
    const int cidx = tid >> 5;                    // 0..15
    for (int cc = cidx; cc < vcols; cc += 16) {
      const int ncol = n0 + vs0 + cc;
      const int h = (ncol >> 6) & 15;
      const int dh = ncol & 63;
      const bf16x8 v = *(const bf16x8*)(lds + cc * 264 + mg * 8);
      *(bf16x8*)(vT_out + ((size_t)(bI * 16 + h) * 64 + dh) * 2048 + s0m + mg * 8) = v;
    }
  }
}

// ---------------- 256x128 6-phase output GEMM: out = attn * Wo^T + bo (fp32) ----------------
// Epilogue: per 128-row half, stage C+bias into LDS fp32 [128][132] (132
// stride -> only 2-way bank aliasing, free), then 512 threads store float4
// covering contiguous 512B rows (full-line coalesced 32MB write).
__global__ __launch_bounds__(512) void gemm_o_256(
    const u16* __restrict__ A, const u16* __restrict__ Bw,
    const float* __restrict__ bo, float* __restrict__ out)
{
  __shared__ u16 lds[49152];   // 96 KiB (= 24576 floats for epilogue restage)

  const int tid = threadIdx.x;
  const int lane = tid & 63;
  const int wave = tid >> 6;

  const int bid = (int)blockIdx.x;
  const int xcd = bid & 7;
  const int idx = bid >> 3;                 // 0..31
  const int mt = (xcd << 2) | (idx & 3);    // 0..31
  const int nt = idx >> 2;                  // 0..7
  const int m0 = mt << 8;
  const int n0 = nt << 7;

  const int warp_m = wave >> 2;
  const int warp_n = wave & 3;
  const int wm = warp_m << 7;
  const int wn = warp_n << 5;               // 0,32,64,96
  const int fr = lane & 15;
  const int g  = lane >> 4;

  const int srow = tid >> 3;
  const int schk = ((tid & 7) ^ (srow & 7)) << 3;
  const u16* pA = A  + (size_t)(m0 + srow) * 1024 + schk;
  const u16* pB = Bw + (size_t)(n0 + srow) * 1024 + schk;

  const int rsw0 = ((g    ) ^ (fr & 7)) << 3;
  const int rsw1 = ((g ^ 4) ^ (fr & 7)) << 3;

  const u16* Ab0 = lds + (size_t)(wm + fr) * 64;
  const u16* Bb0 = lds + 16384 + (size_t)(wn + fr) * 64;
  const u16* Ab1 = Ab0 + 24576;
  const u16* Bb1 = Bb0 + 24576;

  f32x4 acc[8][2];
  const f32x4 zero = {0.f, 0.f, 0.f, 0.f};
#pragma unroll
  for (int i = 0; i < 8; i++)
#pragma unroll
    for (int j = 0; j < 2; j++) acc[i][j] = zero;

  bf16x8 a_[8][2];
  bf16x8 b_[2][2];

  auto stageA = [&](int kt, int buf, int half) {   // 2 loads (128 rows)
    const u16* src = pA + (size_t)half * 131072 + (kt << 6);
    u16* dst = lds + buf * 24576 + half * 8192 + tid * 8;
    llds16(src, dst);
    llds16(src + 65536, dst + 4096);
  };
  auto stageB = [&](int kt, int buf) {             // 2 loads (128 rows)
    const u16* src = pB + (kt << 6);
    u16* dst = lds + buf * 24576 + 16384 + tid * 8;
    llds16(src, dst);
    llds16(src + 65536, dst + 4096);
  };
  auto loadA4 = [&](const u16* Ab, int ib) {
#pragma unroll
    for (int ii = 0; ii < 4; ii++) {
      const u16* r = Ab + (ib + ii) * 1024;
      a_[ib + ii][0] = *(const bf16x8*)(r + rsw0);
      a_[ib + ii][1] = *(const bf16x8*)(r + rsw1);
    }
  };
  auto loadB2 = [&](const u16* Bb) {
#pragma unroll
    for (int jj = 0; jj < 2; jj++) {
      const u16* r = Bb + jj * 1024;
      b_[jj][0] = *(const bf16x8*)(r + rsw0);
      b_[jj][1] = *(const bf16x8*)(r + rsw1);
    }
  };
  auto mfma16 = [&](int ib) {
    __builtin_amdgcn_s_setprio(1);
#pragma unroll
    for (int jj = 0; jj < 2; jj++)
#pragma unroll
      for (int ii = 0; ii < 4; ii++) {
        acc[ib+ii][jj] = __builtin_amdgcn_mfma_f32_16x16x32_bf16(
            a_[ib+ii][0], b_[jj][0], acc[ib+ii][jj], 0, 0, 0);
        acc[ib+ii][jj] = __builtin_amdgcn_mfma_f32_16x16x32_bf16(
            a_[ib+ii][1], b_[jj][1], acc[ib+ii][jj], 0, 0, 0);
      }
    __builtin_amdgcn_s_setprio(0);
  };
  auto mfma8 = [&](int ib, int jj) {
    __builtin_amdgcn_s_setprio(1);
#pragma unroll
    for (int ii = 0; ii < 4; ii++) {
      acc[ib+ii][jj] = __builtin_amdgcn_mfma_f32_16x16x32_bf16(
          a_[ib+ii][0], b_[jj][0], acc[ib+ii][jj], 0, 0, 0);
      acc[ib+ii][jj] = __builtin_amdgcn_mfma_f32_16x16x32_bf16(
          a_[ib+ii][1], b_[jj][1], acc[ib+ii][jj], 0, 0, 0);
    }
    __builtin_amdgcn_s_setprio(0);
  };

  // prologue: buf0 <- K-tile 0 (A0,A1,B = 6 loads), buf1.A0 <- K-tile 1 (2)
  stageA(0, 0, 0);
  stageA(0, 0, 1);
  stageB(0, 0);
  stageA(1, 1, 0);
  asm volatile("s_waitcnt vmcnt(2)" ::: "memory");
  __builtin_amdgcn_s_barrier();

  const int NTI = 8;   // K / 128
  for (int t = 0; t < NTI; ++t) {
    const bool st = (t < NTI - 1);
    const int ka = 2 * t + 1;
    const int kb = 2 * t + 2;
    const int kc = 2 * t + 3;

    // ---- K-tile 2t from buf0 ----
    loadA4(Ab0, 0); loadB2(Bb0);
    stageA(ka, 1, 1);
    __builtin_amdgcn_s_barrier();
    mfma16(0);
    __builtin_amdgcn_s_barrier();
    loadA4(Ab0, 4);
    stageB(ka, 1);
    __builtin_amdgcn_s_barrier();
    mfma8(4, 0);
    __builtin_amdgcn_s_barrier();
    if (st) stageA(kb, 0, 0);
    __builtin_amdgcn_s_barrier();
    mfma8(4, 1);
    if (st) { asm volatile("s_waitcnt vmcnt(2)" ::: "memory"); }
    else    { asm volatile("s_waitcnt vmcnt(0)" ::: "memory"); }
    __builtin_amdgcn_s_barrier();

    // ---- K-tile 2t+1 from buf1 ----
    loadA4(Ab1, 0); loadB2(Bb1);
    if (st) stageA(kb, 0, 1);
    __builtin_amdgcn_s_barrier();
    mfma16(0);
    __builtin_amdgcn_s_barrier();
    loadA4(Ab1, 4);
    if (st) stageB(kb, 0);
    __builtin_amdgcn_s_barrier();
    mfma8(4, 0);
    __builtin_amdgcn_s_barrier();
    if (st) stageA(kc, 1, 0);
    __builtin_amdgcn_s_barrier();
    mfma8(4, 1);
    if (st) { asm volatile("s_waitcnt vmcnt(2)" ::: "memory"); }
    __builtin_amdgcn_s_barrier();
  }

  // ---- epilogue: bias -> LDS fp32 [128][132] per half -> coalesced float4 stores ----
  float* const ldsf = (float*)lds;
  const float bb0 = bo[n0 + wn + fr];
  const float bb1 = bo[n0 + wn + 16 + fr];
#pragma unroll
  for (int h = 0; h < 2; h++) {
    __syncthreads();                       // prev half's reads (or main loop) drained
    if (warp_m == h) {
#pragma unroll
      for (int i = 0; i < 8; i++) {
#pragma unroll
        for (int r = 0; r < 4; r++) {
          const int row = i * 16 + g * 4 + r;     // 0..127 within half
          ldsf[row * 132 + wn + fr]      = acc[i][0][r] + bb0;
          ldsf[row * 132 + wn + 16 + fr] = acc[i][1][r] + bb1;
        }
      }
    }
    __syncthreads();
    // 16384 floats = 4096 float4; 512 threads x 8 passes; row = 32 float4
#pragma unroll
    for (int p = 0; p < 8; p++) {
      const int fid = p * 512 + tid;
      const int row = fid >> 5;
      const int c4 = fid & 31;
      const float4 v = *(const float4*)(ldsf + row * 132 + (c4 << 2));
      *(float4*)(out + (size_t)(m0 + h * 128 + row) * 1024 + n0 + (c4 << 2)) = v;
    }
  }
}

// ---------------- MFMA flash attention: single q-tile, PV deferred, 3 blocks/CU ----------------
// Round-9 proven loop.  qt-priority ladder; O-epilogue restaged through the
// dead p_s buffer (wave-private rows, in-order LDS -> no barrier) for
// 16B/lane coalesced stores.
__global__ __launch_bounds__(256, 3) void attn_fa(
    const u16* __restrict__ Qb, const u16* __restrict__ Kb,
    const u16* __restrict__ VT, u16* __restrict__ Ob)
{
  __shared__ u16 k_s[2 * 4096];      // dbuf [kn][d], 16B-chunks XOR'd by row
  __shared__ u16 v_s[2 * 4096];      // dbuf [dn][k], same swizzle (lags K by 1 tile)
  __shared__ u16 p_s[128 * 72];      // [q][key] bf16, stride 72 (wave-private rows)
  __shared__ float l_s[128];

  const int tid = threadIdx.x;
  const int lane = tid & 63;
  const int wave = tid >> 6;
  const int bid = (int)blockIdx.x;
  const int qt = 15 - (bid >> 6);               // big tiles first
  const int bh = (((bid >> 3) & 7) << 3) | (bid & 7);   // bh % 8 == bid % 8 (XCD)
  const size_t head = (size_t)bh << 17;
  const int fr = lane & 15;
  const int g = lane >> 4;
  const int k8 = g << 3;
  const int q0 = qt << 7;
  const int wrow = wave << 5;

  // critical-path priority ladder (wave-uniform; persists for the kernel)
  if (qt >= 14)     __builtin_amdgcn_s_setprio(2);
  else if (qt >= 8) __builtin_amdgcn_s_setprio(1);

  // Q fragments (pre-scaled); loop-invariant B-operands
  bf16x8 aq[2][2];
#pragma unroll
  for (int f = 0; f < 2; f++) {
    const u16* qp = Qb + head + (size_t)(q0 + wrow + (f << 4) + fr) * 64;
    aq[f][0] = *(const bf16x8*)(qp + k8);
    aq[f][1] = *(const bf16x8*)(qp + 32 + k8);
  }

  // ---- hoisted lane-constant offsets ----
  const int r0 = tid >> 3, c0 = tid & 7;
  const int r1 = 32 + r0;
  const int koff0 = r0 * 64 + (((c0 ^ r0) & 7) << 3);     // K staging src offsets
  const int koff1 = r1 * 64 + (((c0 ^ r1) & 7) << 3);
  const int voff0 = r0 * 2048 + (((c0 ^ r0) & 7) << 3);   // V^T staging src offsets
  const int voff1 = r1 * 2048 + (((c0 ^ r1) & 7) << 3);
  int kaddr[4][2], vaddr[2][4];                           // fragment-read offsets
#pragma unroll
  for (int j = 0; j < 4; j++) {
    const int kn = (j << 4) + fr;
    kaddr[j][0] = kn * 64 + (((g ^ kn) & 7) << 3);
    kaddr[j][1] = kn * 64 + ((((g + 4) ^ kn) & 7) << 3);
#pragma unroll
    for (int s2 = 0; s2 < 2; s2++)
      vaddr[s2][j] = kn * 64 + ((((s2 << 2) + g) ^ (kn & 7)) << 3);
  }
  u16* const prow0 = p_s + (wrow + fr) * 72;        // q row f=0 (write cols & read k8)
  u16* const prow1 = p_s + (wrow + 16 + fr) * 72;   // q row f=1
  const u16* Kbase = Kb + head;
  const u16* Vbase = VT + head;

  auto issueK = [&](int jt2, int buf) {
    const u16* Kt = Kbase + ((size_t)jt2 << 12);
    llds16(Kt + koff0, k_s + (buf << 12) + tid * 8);
    llds16(Kt + koff1, k_s + (buf << 12) + 2048 + tid * 8);
  };
  auto issueV = [&](int jt2, int buf) {
    const u16* Vt = Vbase + (jt2 << 6);
    llds16(Vt + voff0, v_s + (buf << 12) + tid * 8);
    llds16(Vt + voff1, v_s + (buf << 12) + 2048 + tid * 8);
  };

  f32x4 o_acc[2][4];
  const f32x4 zero = {0.f, 0.f, 0.f, 0.f};
#pragma unroll
  for (int f = 0; f < 2; f++)
#pragma unroll
    for (int j = 0; j < 4; j++) o_acc[f][j] = zero;
  float l_run[2] = {0.f, 0.f};

  const int jmax = 2 * qt + 1;                 // jmax+1 iterations (even count)
  const int jt_diag = 2 * qt + (wave >> 1);    // per-wave diagonal tile

  auto do_pv = [&](const u16* vs) {
#pragma unroll
    for (int s2 = 0; s2 < 2; s2++) {
      const bf16x8 ap0 = *(const bf16x8*)(prow0 + (s2 << 5) + k8);
      const bf16x8 ap1 = *(const bf16x8*)(prow1 + (s2 << 5) + k8);
#pragma unroll
      for (int j = 0; j < 4; j++) {
        const bf16x8 bv = *(const bf16x8*)(vs + vaddr[s2][j]);
        o_acc[0][j] = __builtin_amdgcn_mfma_f32_16x16x32_bf16(ap0, bv, o_acc[0][j], 0, 0, 0);
        o_acc[1][j] = __builtin_amdgcn_mfma_f32_16x16x32_bf16(ap1, bv, o_acc[1][j], 0, 0, 0);
      }
    }
  };

  auto do_s = [&](const u16* ks, bool dodiag, int jt) {
    f32x4 s_acc[2][4];
#pragma unroll
    for (int f = 0; f < 2; f++)
#pragma unroll
      for (int j = 0; j < 4; j++) s_acc[f][j] = zero;
#pragma unroll
    for (int j = 0; j < 4; j++) {
      const bf16x8 ka0 = *(const bf16x8*)(ks + kaddr[j][0]);
      const bf16x8 ka1 = *(const bf16x8*)(ks + kaddr[j][1]);
      s_acc[0][j] = __builtin_amdgcn_mfma_f32_16x16x32_bf16(ka0, aq[0][0], s_acc[0][j], 0, 0, 0);
      s_acc[0][j] = __builtin_amdgcn_mfma_f32_16x16x32_bf16(ka1, aq[0][1], s_acc[0][j], 0, 0, 0);
      s_acc[1][j] = __builtin_amdgcn_mfma_f32_16x16x32_bf16(ka0, aq[1][0], s_acc[1][j], 0, 0, 0);
      s_acc[1][j] = __builtin_amdgcn_mfma_f32_16x16x32_bf16(ka1, aq[1][1], s_acc[1][j], 0, 0, 0);
    }
#pragma unroll
    for (int f = 0; f < 2; f++) {
      const int qa = q0 + wrow + (f << 4) + fr;
      u16* prow = (f == 0) ? prow0 : prow1;
      if (dodiag) {
#pragma unroll
        for (int j = 0; j < 4; j++) {
          const int kb = (jt << 6) + (j << 4) + (g << 2);
          float p0 = (kb + 0 > qa) ? 0.f : __builtin_amdgcn_exp2f(s_acc[f][j][0]);
          float p1 = (kb + 1 > qa) ? 0.f : __builtin_amdgcn_exp2f(s_acc[f][j][1]);
          float p2 = (kb + 2 > qa) ? 0.f : __builtin_amdgcn_exp2f(s_acc[f][j][2]);
          float p3 = (kb + 3 > qa) ? 0.f : __builtin_amdgcn_exp2f(s_acc[f][j][3]);
          l_run[f] += (p0 + p1) + (p2 + p3);
          union { __hip_bfloat162 h; unsigned u; } ca, cb;
          ca.h = __float22bfloat162_rn(make_float2(p0, p1));
          cb.h = __float22bfloat162_rn(make_float2(p2, p3));
          *(uint2*)(prow + (j << 4) + (g << 2)) = make_uint2(ca.u, cb.u);
        }
      } else {
#pragma unroll
        for (int j = 0; j < 4; j++) {
          float p0 = __builtin_amdgcn_exp2f(s_acc[f][j][0]);
          float p1 = __builtin_amdgcn_exp2f(s_acc[f][j][1]);
          float p2 = __builtin_amdgcn_exp2f(s_acc[f][j][2]);
          float p3 = __builtin_amdgcn_exp2f(s_acc[f][j][3]);
          l_run[f] += (p0 + p1) + (p2 + p3);
          union { __hip_bfloat162 h; unsigned u; } ca, cb;
          ca.h = __float22bfloat162_rn(make_float2(p0, p1));
          cb.h = __float22bfloat162_rn(make_float2(p2, p3));
          *(uint2*)(prow + (j << 4) + (g << 2)) = make_uint2(ca.u, cb.u);
        }
      }
    }
  };

  issueK(0, 0);   // prime K pipeline (V(0) issued inside iteration 0)

  for (int jt = 0; jt <= jmax; jt++) {
    const int kb = jt & 1;
    __syncthreads();                       // K(jt) + V(jt-1) landed; LDS reads drained
    if (jt < jmax) issueK(jt + 1, kb ^ 1);
    issueV(jt, kb);
    if (jt > 0 && jt - 1 <= jt_diag) do_pv(v_s + ((kb ^ 1) << 12));   // deferred PV
    if (jt <= jt_diag) do_s(k_s + (kb << 12), jt == jt_diag, jt);
  }
  __syncthreads();                         // V(jmax) landed
  if (jt_diag == jmax) do_pv(v_s + ((jmax & 1) << 12));   // waves 2,3 final PV

  // ---- epilogue (all wave-private; no barriers needed) ----
  // reduce l (q-col lives in lanes fr, fr+16, fr+32, fr+48)
#pragma unroll
  for (int f = 0; f < 2; f++) {
    float l = l_run[f];
    l += __shfl_xor(l, 16);
    l += __shfl_xor(l, 32);
    if (g == 0) l_s[wrow + (f << 4) + fr] = l;   // wave-private slot
  }
  // scale + restage O through p_s (this wave's rows; dead after final do_pv)
#pragma unroll
  for (int f = 0; f < 2; f++) {
#pragma unroll
    for (int r = 0; r < 4; r++) {
      const int qloc = wrow + (f << 4) + (g << 2) + r;
      const float inv = 1.f / l_s[qloc];
#pragma unroll
      for (int j = 0; j < 4; j++)
        p_s[qloc * 72 + (j << 4) + fr] = f2bf(o_acc[f][j][r] * inv);
    }
  }
  // coalesced store: wave's 32 rows x 64 cols, 16B/lane (32B contiguous per row-pair)
  const int b = bh >> 4, h = bh & 15;
  const int rowl = wrow + (lane >> 1);
  const int colh = (lane & 1) << 3;
  u16* const obase = Ob + ((size_t)b * 2048 + q0 + rowl) * 1024 + (h << 6);
#pragma unroll
  for (int k = 0; k < 4; k++) {
    const int c0 = (k << 4) + colh;
    const bf16x8 v = *(const bf16x8*)(p_s + rowl * 72 + c0);
    *(bf16x8*)(obase + c0) = v;
  }
}

// ---------------- launch ----------------
extern "C" void kernel_launch(void* const* d_in, const int* in_sizes, int n_in,
                              void* d_out, int out_size, void* d_ws, size_t ws_size,
                              hipStream_t stream) {
  const float* x  = (const float*)d_in[0];
  const float* Wq = (const float*)d_in[1];
  const float* bq = (const float*)d_in[2];
  const float* Wk = (const float*)d_in[3];
  const float* bk = (const float*)d_in[4];
  const float* Wv = (const float*)d_in[5];
  const float* bv = (const float*)d_in[6];
  const float* Wo = (const float*)d_in[7];
  const float* bo = (const float*)d_in[8];
  float* out = (float*)d_out;

  char* ws = (char*)d_ws;
  u16* xb    = (u16*)(ws);                 // 16 MB; dead after QKV GEMM
  u16* attnb = (u16*)(ws);                 // aliases xb (dead by then)
  u16* wqkv  = (u16*)(ws + 16777216);      // 6 MB packed q|k|v weights
  u16* wo    = (u16*)(ws + 23068672);      // 2 MB
  u16* qkv   = (u16*)(ws + 25165824);      // 32 MB: Q | K  [BH][S][DH]
  u16* vT    = (u16*)(ws + 58720256);      // 16 MB: V^T [BH][64][S]
  // total ws: 75,497,472 B

  // fused cast: x + all 4 weight matrices, one launch
  cast_all_kernel<<<12288, 256, 0, stream>>>(x, Wq, Wk, Wv, Wo, xb, wqkv, wo);

  // fused QKV projection + V-transpose: M=8192, N=3072, K=1024
  gemm_qkv_256<<<dim3(512), 512, 0, stream>>>(xb, wqkv, bq, bk, bv, qkv, vT);

  // MFMA flash attention (single q-tile/block, big-first dispatch, 3 blocks/CU,
  // qt-priority ladder, coalesced O-epilogue); writes attnb over dead xb
  attn_fa<<<dim3(1024), 256, 0, stream>>>(qkv, qkv + 8388608, vT, attnb);

  // output projection: M=8192, N=1024, K=1024 (256x128 6-phase, 1 clean round,
  // LDS-restaged coalesced fp32 epilogue)
  gemm_o_256<<<dim3(256), 512, 0, stream>>>(attnb, wo, bo, out);
}